// Round 2
// baseline (33.085 us; speedup 1.0000x reference)
//
#include <hip/hip_runtime.h>

// CLUB loss, algebraically collapsed to O(N*d) streaming reductions:
//   loss = -0.5/N * S_pos + 0.5/N^2 * ( dot(S_invv, S_x2) - 2*dot(S_muinvv, S_x) + N*S_c )
// where S_* are sums over the N=16384 rows (d=64 columns).
//
// Two nodes, no memset: pass1 blocks write 258-double partial slots into d_ws
// (plain stores, poison-immune); finalize reduces slots and writes the scalar.

#define NROWS  16384
#define DDIM   64
#define NTILES 256          // 64 rows per tile
#define SLOTW  258          // 4*64 vector partials + 2 scalars

__global__ __launch_bounds__(256) void club_pass1(const float* __restrict__ x,
                                                  const float* __restrict__ mu,
                                                  const float* __restrict__ logvar,
                                                  double* __restrict__ slots, int grid) {
    __shared__ float  xt[64 * 65];   // padded transpose tile (2-way bank access = free)
    __shared__ double red[256];

    const int tid = threadIdx.x;
    const int d   = tid & 63;        // lane -> column d (coalesced mu/logvar)
    const int j0  = (tid >> 6) * 16; // wave -> row sub-block

    double a_x = 0.0, a_x2 = 0.0, a_iv = 0.0, a_miv = 0.0, a_c = 0.0, a_pos = 0.0;

    for (int tile = blockIdx.x; tile < NTILES; tile += grid) {
        const int i0  = tile * 64;
        const int b   = i0 >> 10;        // h*w = 1024 rows per batch image
        const int hw0 = i0 & 1023;
        const float* xb = x + (size_t)b * 65536 + hw0;

        __syncthreads();                 // protect xt from prior-iter readers
        #pragma unroll
        for (int t = tid; t < 4096; t += 256) {
            const int dd = t >> 6, j = t & 63;
            xt[dd * 65 + j] = xb[(size_t)dd * 1024 + j];   // coalesced rows
        }
        __syncthreads();

        #pragma unroll
        for (int k = 0; k < 16; ++k) {
            const int j  = j0 + k;                   // wave-uniform row
            const float xv = xt[d * 65 + j];
            const int idx  = (i0 + j) * DDIM + d;    // coalesced
            const float m  = mu[idx];
            const float lv = logvar[idx];
            const float iv = expf(-lv);
            const float t2 = xv - m;
            a_x   += (double)xv;
            a_x2  += (double)(xv * xv);
            a_iv  += (double)iv;
            a_miv += (double)(m * iv);
            a_c   += (double)(m * m * iv);
            a_pos += (double)(t2 * t2 * iv);
        }
    }

    double* slot = slots + (size_t)blockIdx.x * SLOTW;

    #define VR(val, base)                                                              \
        red[tid] = (val); __syncthreads();                                             \
        if (tid < 64) slot[(base) + tid] =                                             \
            red[tid] + red[tid + 64] + red[tid + 128] + red[tid + 192];                \
        __syncthreads();
    VR(a_x,   0)
    VR(a_x2,  64)
    VR(a_iv,  128)
    VR(a_miv, 192)
    #undef VR

    red[tid] = a_c; __syncthreads();
    if (tid < 64) {
        double s = red[tid] + red[tid + 64] + red[tid + 128] + red[tid + 192];
        #pragma unroll
        for (int off = 32; off > 0; off >>= 1) s += __shfl_down(s, off, 64);
        if (tid == 0) slot[256] = s;
    }
    __syncthreads();
    red[tid] = a_pos; __syncthreads();
    if (tid < 64) {
        double s = red[tid] + red[tid + 64] + red[tid + 128] + red[tid + 192];
        #pragma unroll
        for (int off = 32; off > 0; off >>= 1) s += __shfl_down(s, off, 64);
        if (tid == 0) slot[257] = s;
    }
}

__global__ __launch_bounds__(256) void club_finalize(const double* __restrict__ slots,
                                                     int grid, float* __restrict__ out) {
    __shared__ double red[256];
    __shared__ double S[258];
    const int t = threadIdx.x;
    const int d = t & 63, q = t >> 6;

    double v0 = 0, v1 = 0, v2 = 0, v3 = 0, pc = 0, pp = 0;
    for (int s = q; s < grid; s += 4) {
        const double* p = slots + (size_t)s * SLOTW;
        v0 += p[d]; v1 += p[64 + d]; v2 += p[128 + d]; v3 += p[192 + d];
    }
    for (int s = t; s < grid; s += 256) {
        const double* p = slots + (size_t)s * SLOTW;
        pc += p[256]; pp += p[257];
    }

    #define VR2(val, base)                                                             \
        red[t] = (val); __syncthreads();                                               \
        if (t < 64) S[(base) + t] =                                                    \
            red[t] + red[t + 64] + red[t + 128] + red[t + 192];                        \
        __syncthreads();
    VR2(v0, 0)
    VR2(v1, 64)
    VR2(v2, 128)
    VR2(v3, 192)
    #undef VR2

    red[t] = pc; __syncthreads();
    if (t < 64) {
        double s = red[t] + red[t + 64] + red[t + 128] + red[t + 192];
        #pragma unroll
        for (int off = 32; off > 0; off >>= 1) s += __shfl_down(s, off, 64);
        if (t == 0) S[256] = s;
    }
    __syncthreads();
    red[t] = pp; __syncthreads();
    if (t < 64) {
        double s = red[t] + red[t + 64] + red[t + 128] + red[t + 192];
        #pragma unroll
        for (int off = 32; off > 0; off >>= 1) s += __shfl_down(s, off, 64);
        if (t == 0) S[257] = s;
    }
    __syncthreads();

    if (t < 64) {
        double term = S[128 + t] * S[64 + t] - 2.0 * S[192 + t] * S[t];
        #pragma unroll
        for (int off = 32; off > 0; off >>= 1) term += __shfl_down(term, off, 64);
        if (t == 0) {
            const double Nd   = (double)NROWS;
            const double sumD = term + Nd * S[256];
            out[0] = (float)(-0.5 / Nd * S[257] + 0.5 / (Nd * Nd) * sumD);
        }
    }
}

extern "C" void kernel_launch(void* const* d_in, const int* in_sizes, int n_in,
                              void* d_out, int out_size, void* d_ws, size_t ws_size,
                              hipStream_t stream) {
    const float* x      = (const float*)d_in[0];
    const float* mu     = (const float*)d_in[1];
    const float* logvar = (const float*)d_in[2];
    float*  out   = (float*)d_out;
    double* slots = (double*)d_ws;

    int grid = 256;
    const size_t need = (size_t)grid * SLOTW * sizeof(double);
    if (ws_size < need) {
        grid = (int)(ws_size / (SLOTW * sizeof(double)));
        if (grid < 1) grid = 1;
        if (grid > 256) grid = 256;
    }

    club_pass1<<<grid, 256, 0, stream>>>(x, mu, logvar, slots, grid);
    club_finalize<<<1, 256, 0, stream>>>(slots, grid, out);
}